// Round 5
// baseline (55.948 us; speedup 1.0000x reference)
//
#include <hip/hip_runtime.h>

#define DI __device__ __forceinline__

constexpr int BATCH = 256;
constexpr int INF   = 4096;   // in_features
constexpr int NGRP  = 1024;   // INF/4
constexpr int MOUT  = 4096;   // out_features

constexpr int BM = 64, BN = 64;   // block output tile
constexpr int WKS = 8;            // k-slices (one per wave pair)
constexpr int WK  = INF / WKS;    // 512 k per wave
constexpr int NH  = WK / 32;      // 16 half-steps of k=32
constexpr int RS  = 36;           // reduction row stride (f32), 16B-aligned

using bf16x8 = __attribute__((ext_vector_type(8))) short;
using f32x4  = __attribute__((ext_vector_type(4))) float;

// D4 half-codebook, stored as 2x the actual values (int8); actual = v * 0.5
__device__ __constant__ signed char D4_I8[512] = {
     0, 0, 0, 0,  -4, 0, 0, 0,  -2,-2,-2,-2,  -2,-2,-2, 0,  -2,-2,-2, 2,  -2,-2, 0,-2,  -2,-2, 0, 0,  -2,-2, 0, 2,
    -2,-2, 2,-2,  -2,-2, 2, 0,  -2,-2, 2, 2,  -2, 0,-2,-2,  -2, 0,-2, 0,  -2, 0,-2, 2,  -2, 0, 0,-2,  -2, 0, 0, 0,
    -2, 0, 0, 2,  -2, 0, 2,-2,  -2, 0, 2, 0,  -2, 0, 2, 2,  -2, 2,-2,-2,  -2, 2,-2, 0,  -2, 2,-2, 2,  -2, 2, 0,-2,
    -2, 2, 0, 0,  -2, 2, 0, 2,  -2, 2, 2,-2,  -2, 2, 2, 0,  -2, 2, 2, 2,   0,-4, 0, 0,   0,-2,-2,-2,   0,-2,-2, 0,
     0,-2,-2, 2,   0,-2, 0,-2,   0,-2, 0, 0,   0,-2, 0, 2,   0,-2, 2,-2,   0,-2, 2, 0,   0,-2, 2, 2,   0, 0,-4, 0,
     0, 0,-2,-2,   0, 0,-2, 0,   0, 0,-2, 2,   0, 0, 0,-4,   0, 0, 0,-2,
    -3,-1,-3,-1,  -3,-1,-3, 1,  -3,-1,-1,-3,  -3,-1,-1,-1,  -3,-1,-1, 1,  -3,-1,-1, 3,  -3,-1, 1,-3,  -3,-1, 1,-1,
    -3,-1, 1, 1,  -3,-1, 1, 3,  -3,-1, 3,-1,  -3,-1, 3, 1,  -3, 1,-3,-1,  -3, 1,-3, 1,  -3, 1,-1,-3,  -3, 1,-1,-1,
    -3, 1,-1, 1,  -3, 1,-1, 3,  -3, 1, 1,-3,  -3, 1, 1,-1,  -3, 1, 1, 1,  -3, 1, 1, 3,  -3, 1, 3,-1,  -3, 1, 3, 1,
    -3, 3,-1,-1,  -3, 3, 1,-1,  -3, 3, 1, 1,  -1,-3,-3,-1,  -1,-3,-3, 1,  -1,-3,-1,-3,  -1,-3,-1,-1,  -1,-3,-1, 1,
    -1,-3,-1, 3,  -1,-3, 1,-3,  -1,-3, 1,-1,  -1,-3, 1, 1,  -1,-3, 1, 3,  -1,-3, 3,-1,  -1,-3, 3, 1,  -1,-1,-3,-3,
    -1,-1,-3,-1,  -1,-1,-3, 1,  -1,-1,-3, 3,  -1,-1,-1,-3,  -1,-1,-1,-1,  -1,-1,-1, 1,  -1,-1,-1, 3,  -1,-1, 1,-3,
    -1,-1, 1,-1,  -1,-1, 1, 1,  -1,-1, 1, 3,  -1,-1, 3,-3,  -1,-1, 3,-1,  -1,-1, 3, 1,  -1,-1, 3, 3,  -1, 1,-3,-3,
    -1, 1,-3,-1,  -1, 1,-3, 1,  -1, 1,-3, 3,  -1, 1,-1,-3,  -1, 1,-1,-1,  -1, 1,-1, 1,  -1, 1,-1, 3,  -1, 1, 1,-3,
    -1, 1, 1,-1,  -1, 1, 1, 1,  -1, 1, 1, 3,  -1, 1, 3,-3,  -1, 1, 3,-1,  -1, 1, 3, 1,  -1, 1, 3, 3,  -1, 3,-3,-1,
    -1, 3,-3, 1,  -1, 3,-1,-3,  -1, 3,-1,-1,  -1, 3,-1, 1,  -1, 3,-1, 3,  -1, 3, 1,-3,  -1, 3, 1,-1,  -1, 3, 1, 1,
    -1, 3, 1, 3,  -1, 3, 3,-1,  -1, 3, 3, 1
};

DI unsigned short f2bf(float f) {  // f32 -> bf16 bits, round-to-nearest-even
  unsigned int u = __float_as_uint(f);
  u += 0x7fffu + ((u >> 16) & 1u);
  return (unsigned short)(u >> 16);
}

// Build Xs = input * scaleW_DSC * Qscales (bf16) into d_ws.
__global__ __launch_bounds__(256) void prep_kernel(
    const float* __restrict__ inp, const float* __restrict__ sw,
    const float* __restrict__ qs, unsigned short* __restrict__ xs) {
  int i = blockIdx.x * 256 + threadIdx.x;      // group-of-4 index, 262144 total
  int g = i & (NGRP - 1);
  float4 v = reinterpret_cast<const float4*>(inp)[i];
  float4 s = reinterpret_cast<const float4*>(sw)[g];
  float  q = qs[g];
  ushort4 o;
  o.x = f2bf(v.x * s.x * q);
  o.y = f2bf(v.y * s.y * q);
  o.z = f2bf(v.z * s.z * q);
  o.w = f2bf(v.w * s.w * q);
  reinterpret_cast<ushort4*>(xs)[i] = o;
}

// Fused dequant-GEMM. One 1024-thread block (16 waves = 4 waves/SIMD) per
// 64x64 output tile. Waves split 8 k-slices x 2 n-halves (acc = 32 VGPR ->
// fits 128-VGPR cap for 4 waves/SIMD). 3-stage LDS tree reduction (74 KB),
// single coalesced float4 store, no atomics.
__global__ __launch_bounds__(1024, 4) void gemm_kernel(
    const unsigned short* __restrict__ xs, const int* __restrict__ qidx,
    float* __restrict__ out) {
  __shared__ unsigned long long tbl[256];   // 2 KB, sign-folded bf16x4 codebook
  __shared__ float red[8][BM * RS];         // 8 x 9.2 KB partial half-tiles

  const int tid  = threadIdx.x;
  const int lane = tid & 63;
  const int wave = tid >> 6;                // 0..15
  const int wk   = wave >> 1;               // k-slice 0..7
  const int wn   = wave & 1;                // n-half 0..1
  const int l15  = lane & 15, l4 = lane >> 4;

  // ---- XCD swizzle: the 4 m-blocks of one n-tile share an XCD so the 4x
  // Qidxs re-read is an L2 hit (2 MB Qidxs region per XCD).
  const int bid = blockIdx.x;               // 0..255
  const int nt  = (bid & 7) * 8 + ((bid >> 3) & 7);   // 0..63
  const int mt  = bid >> 6;                           // 0..3
  const int m0 = mt * BM, n0 = nt * BN;

  // ---- signed codebook table: tbl[i] = 4 packed bf16, tbl[i+128] = -tbl[i]
  if (tid < 256) {
    int r = tid & 127, sg = tid >> 7;
    unsigned long long v = 0;
#pragma unroll
    for (int j = 0; j < 4; ++j) {
      float f = (float)D4_I8[r * 4 + j] * 0.5f;
      unsigned int b = __float_as_uint(f) ^ (sg ? 0x80000000u : 0u);
      v |= (unsigned long long)(b >> 16) << (16 * j);
    }
    tbl[tid] = v;
  }
  __syncthreads();

  // ---- per-lane bases for this wave's k-slice / n-half
  const int k0 = wk * WK;
  const unsigned short* ab = xs + (size_t)(m0 + l15) * INF + k0 + l4 * 8;
  const int* qb =
      qidx + (size_t)(n0 + wn * 32 + l15) * NGRP + (k0 >> 2) + l4 * 2;

  f32x4  acc[4][2] = {};
  int2   qbuf[3][2] = {};
  bf16x8 abuf[2][4];
  bf16x8 bbuf[2][2];

  auto qload = [&](int s, int t) {
    if (t < NH)
#pragma unroll
      for (int ni = 0; ni < 2; ++ni)
        qbuf[s][ni] = *reinterpret_cast<const int2*>(
            qb + (size_t)ni * 16 * NGRP + t * 8);
  };
  auto aload = [&](int s, int t) {
    if (t < NH)
#pragma unroll
      for (int mi = 0; mi < 4; ++mi)
        abuf[s][mi] = *reinterpret_cast<const bf16x8*>(
            ab + (size_t)mi * 16 * INF + t * 32);
  };
  auto blook = [&](int s, int qs) {   // 4 ds_read_b64 (indices &255 in-bounds)
#pragma unroll
    for (int ni = 0; ni < 2; ++ni) {
      union { unsigned long long u[2]; bf16x8 v; } c;
      c.u[0] = tbl[qbuf[qs][ni].x & 255];
      c.u[1] = tbl[qbuf[qs][ni].y & 255];
      bbuf[s][ni] = c.v;
    }
  };

  // ---- prologue
  qload(0, 0);
  qload(1, 1);
  aload(0, 0);
  blook(0, 0);

  // ---- pipelined k-loop, fully unrolled (all buffer indices static)
#pragma unroll
  for (int t = 0; t < NH; ++t) {
    qload((t + 2) % 3, t + 2);          // indices, 2 ahead
    aload((t + 1) & 1, t + 1);          // A-fragments, 1 ahead
    blook((t + 1) & 1, (t + 1) % 3);    // lookups for t+1 before MFMAs of t
#pragma unroll
    for (int mi = 0; mi < 4; ++mi)
#pragma unroll
      for (int ni = 0; ni < 2; ++ni)
        acc[mi][ni] = __builtin_amdgcn_mfma_f32_16x16x32_bf16(
            abuf[t & 1][mi], bbuf[t & 1][ni], acc[mi][ni], 0, 0, 0);
  }

  // ---- 3-stage tree reduction over the 8 k-slices (per n-half)
  auto wtile = [&](int s) {   // write my 64x32 partial into slot s
    float* rw = &red[s][0];
#pragma unroll
    for (int mi = 0; mi < 4; ++mi)
#pragma unroll
      for (int ni = 0; ni < 2; ++ni)
#pragma unroll
        for (int r = 0; r < 4; ++r)
          rw[(mi * 16 + l4 * 4 + r) * RS + ni * 16 + l15] = acc[mi][ni][r];
  };
  auto atile = [&](int s) {   // add slot s into my accumulator
    const float* rr = &red[s][0];
#pragma unroll
    for (int mi = 0; mi < 4; ++mi)
#pragma unroll
      for (int ni = 0; ni < 2; ++ni)
#pragma unroll
        for (int r = 0; r < 4; ++r)
          acc[mi][ni][r] += rr[(mi * 16 + l4 * 4 + r) * RS + ni * 16 + l15];
  };

  if (wk >= 4) wtile((wk - 4) * 2 + wn);
  __syncthreads();
  if (wk < 4) atile(wk * 2 + wn);
  __syncthreads();
  if (wk == 2 || wk == 3) wtile((wk - 2) * 2 + wn);
  __syncthreads();
  if (wk < 2) atile(wk * 2 + wn);
  __syncthreads();
  if (wk == 1) wtile(wn);
  __syncthreads();
  if (wk == 0) { atile(wn); wtile(wn); }   // final 64x32 tiles in slots 0,1
  __syncthreads();

  // ---- coalesced copy-out: 1024 threads x 1 float4 (16 KB tile)
  {
    const int row = tid >> 4;        // 0..63
    const int c4  = tid & 15;        // float4 column 0..15
    float4 v = *reinterpret_cast<const float4*>(
        &red[c4 >> 3][row * RS + (c4 & 7) * 4]);
    *reinterpret_cast<float4*>(
        &out[(size_t)(m0 + row) * MOUT + n0 + c4 * 4]) = v;
  }
}

extern "C" void kernel_launch(void* const* d_in, const int* in_sizes, int n_in,
                              void* d_out, int out_size, void* d_ws, size_t ws_size,
                              hipStream_t stream) {
  const float* inp = (const float*)d_in[0];
  const float* sw  = (const float*)d_in[1];
  const float* qs  = (const float*)d_in[2];
  const int*   qi  = (const int*)d_in[3];
  float* out = (float*)d_out;
  unsigned short* xs = (unsigned short*)d_ws;   // 256*4096 bf16 = 2 MB scratch

  prep_kernel<<<(BATCH * INF / 4) / 256, 256, 0, stream>>>(inp, sw, qs, xs);

  constexpr int GRID = (BATCH / BM) * (MOUT / BN);   // 4 * 64 = 256
  gemm_kernel<<<GRID, 1024, 0, stream>>>(xs, qi, out);
}

// Round 6
// 42.223 us; speedup vs baseline: 1.3251x; 1.3251x over previous
//
#include <hip/hip_runtime.h>

#define DI __device__ __forceinline__

constexpr int BATCH = 256;
constexpr int INF   = 4096;   // in_features
constexpr int NGRP  = 1024;   // INF/4
constexpr int MOUT  = 4096;   // out_features

constexpr int BM = 64, BN = 64;   // block output tile
constexpr int WKS = 8;            // k-slices (one per wave pair)
constexpr int WK  = INF / WKS;    // 512 k per wave
constexpr int NH  = WK / 32;      // 16 half-steps of k=32
constexpr int RS  = 36;           // reduction row stride (f32), 16B-aligned

using bf16x8 = __attribute__((ext_vector_type(8))) short;
using f32x4  = __attribute__((ext_vector_type(4))) float;

// D4 half-codebook, stored as 2x the actual values (int8); actual = v * 0.5
__device__ __constant__ signed char D4_I8[512] = {
     0, 0, 0, 0,  -4, 0, 0, 0,  -2,-2,-2,-2,  -2,-2,-2, 0,  -2,-2,-2, 2,  -2,-2, 0,-2,  -2,-2, 0, 0,  -2,-2, 0, 2,
    -2,-2, 2,-2,  -2,-2, 2, 0,  -2,-2, 2, 2,  -2, 0,-2,-2,  -2, 0,-2, 0,  -2, 0,-2, 2,  -2, 0, 0,-2,  -2, 0, 0, 0,
    -2, 0, 0, 2,  -2, 0, 2,-2,  -2, 0, 2, 0,  -2, 0, 2, 2,  -2, 2,-2,-2,  -2, 2,-2, 0,  -2, 2,-2, 2,  -2, 2, 0,-2,
    -2, 2, 0, 0,  -2, 2, 0, 2,  -2, 2, 2,-2,  -2, 2, 2, 0,  -2, 2, 2, 2,   0,-4, 0, 0,   0,-2,-2,-2,   0,-2,-2, 0,
     0,-2,-2, 2,   0,-2, 0,-2,   0,-2, 0, 0,   0,-2, 0, 2,   0,-2, 2,-2,   0,-2, 2, 0,   0,-2, 2, 2,   0, 0,-4, 0,
     0, 0,-2,-2,   0, 0,-2, 0,   0, 0,-2, 2,   0, 0, 0,-4,   0, 0, 0,-2,
    -3,-1,-3,-1,  -3,-1,-3, 1,  -3,-1,-1,-3,  -3,-1,-1,-1,  -3,-1,-1, 1,  -3,-1,-1, 3,  -3,-1, 1,-3,  -3,-1, 1,-1,
    -3,-1, 1, 1,  -3,-1, 1, 3,  -3,-1, 3,-1,  -3,-1, 3, 1,  -3, 1,-3,-1,  -3, 1,-3, 1,  -3, 1,-1,-3,  -3, 1,-1,-1,
    -3, 1,-1, 1,  -3, 1,-1, 3,  -3, 1, 1,-3,  -3, 1, 1,-1,  -3, 1, 1, 1,  -3, 1, 1, 3,  -3, 1, 3,-1,  -3, 1, 3, 1,
    -3, 3,-1,-1,  -3, 3, 1,-1,  -3, 3, 1, 1,  -1,-3,-3,-1,  -1,-3,-3, 1,  -1,-3,-1,-3,  -1,-3,-1,-1,  -1,-3,-1, 1,
    -1,-3,-1, 3,  -1,-3, 1,-3,  -1,-3, 1,-1,  -1,-3, 1, 1,  -1,-3, 1, 3,  -1,-3, 3,-1,  -1,-3, 3, 1,  -1,-1,-3,-3,
    -1,-1,-3,-1,  -1,-1,-3, 1,  -1,-1,-3, 3,  -1,-1,-1,-3,  -1,-1,-1,-1,  -1,-1,-1, 1,  -1,-1,-1, 3,  -1,-1, 1,-3,
    -1,-1, 1,-1,  -1,-1, 1, 1,  -1,-1, 1, 3,  -1,-1, 3,-3,  -1,-1, 3,-1,  -1,-1, 3, 1,  -1,-1, 3, 3,  -1, 1,-3,-3,
    -1, 1,-3,-1,  -1, 1,-3, 1,  -1, 1,-3, 3,  -1, 1,-1,-3,  -1, 1,-1,-1,  -1, 1,-1, 1,  -1, 1,-1, 3,  -1, 1, 1,-3,
    -1, 1, 1,-1,  -1, 1, 1, 1,  -1, 1, 1, 3,  -1, 1, 3,-3,  -1, 1, 3,-1,  -1, 1, 3, 1,  -1, 1, 3, 3,  -1, 3,-3,-1,
    -1, 3,-3, 1,  -1, 3,-1,-3,  -1, 3,-1,-1,  -1, 3,-1, 1,  -1, 3,-1, 3,  -1, 3, 1,-3,  -1, 3, 1,-1,  -1, 3, 1, 1,
    -1, 3, 1, 3,  -1, 3, 3,-1,  -1, 3, 3, 1
};

DI unsigned short f2bf(float f) {  // f32 -> bf16 bits, round-to-nearest-even
  unsigned int u = __float_as_uint(f);
  u += 0x7fffu + ((u >> 16) & 1u);
  return (unsigned short)(u >> 16);
}

// Build Xa = scaled input in fragment-linear layout Xa[k>>5][m][(k>>3)&3][8]
// (bf16). A wave's MFMA A-fragment load is then 1 KB contiguous.
__global__ __launch_bounds__(256) void prep_kernel(
    const float* __restrict__ inp, const float* __restrict__ sw,
    const float* __restrict__ qs, unsigned short* __restrict__ xa) {
  int i  = blockIdx.x * 256 + threadIdx.x;  // slot id, 131072 total
  int j  = i & 3;                           // k-oct within 32-block
  int m  = (i >> 2) & 255;
  int kb = i >> 10;                         // k >> 5
  const float* ip = inp + (size_t)m * INF + kb * 32 + j * 8;
  float4 f0 = *reinterpret_cast<const float4*>(ip);
  float4 f1 = *reinterpret_cast<const float4*>(ip + 4);
  const float* sp = sw + kb * 32 + j * 8;
  float4 s0 = *reinterpret_cast<const float4*>(sp);
  float4 s1 = *reinterpret_cast<const float4*>(sp + 4);
  int g = kb * 8 + j * 2;
  float q0 = qs[g], q1 = qs[g + 1];
  union { unsigned short u[8]; uint4 v; } o;
  o.u[0] = f2bf(f0.x * s0.x * q0); o.u[1] = f2bf(f0.y * s0.y * q0);
  o.u[2] = f2bf(f0.z * s0.z * q0); o.u[3] = f2bf(f0.w * s0.w * q0);
  o.u[4] = f2bf(f1.x * s1.x * q1); o.u[5] = f2bf(f1.y * s1.y * q1);
  o.u[6] = f2bf(f1.z * s1.z * q1); o.u[7] = f2bf(f1.w * s1.w * q1);
  reinterpret_cast<uint4*>(xa)[i] = o.v;   // wave writes 1 KB contiguous
}

// Repack Qidxs (int32 [MOUT][NGRP]) -> Qp u16 [B4=k>>5][n][j=koct] (4 MB).
// u16 = packed byte-indices of groups (2*g2, 2*g2+1), g2 = B4*4+j = k>>3 /... 
// Reads rows 4KB-contiguous, transposes via swizzled LDS, writes contiguous.
__global__ __launch_bounds__(256) void repack_kernel(
    const int* __restrict__ qidx, unsigned short* __restrict__ qp) {
  __shared__ unsigned short lw[16384];     // 32 KB: [B4(128)][n(32)][j(4)]
  const int t  = threadIdx.x;
  const int n0 = blockIdx.x * 32;
  char* lwb = reinterpret_cast<char*>(lw);

  const int b4w   = t >> 1;
  const int cbase = b4w * 256 + ((2 * t) & 3) * 2;  // bits outside [7:3]
  const int xk    = (b4w & 31) << 3;                // swizzle, bits [7:3]
  for (int r = 0; r < 32; ++r) {
    int4 v = *reinterpret_cast<const int4*>(
        qidx + (size_t)(n0 + r) * NGRP + t * 4);    // 4KB contiguous / row
    unsigned p01 = (v.x & 255) | ((v.y & 255) << 8) |
                   ((v.z & 255) << 16) | ((unsigned)(v.w & 255) << 24);
    *reinterpret_cast<unsigned*>(lwb + cbase + ((r * 8) ^ xk)) = p01;
  }
  __syncthreads();
  for (int it = 0; it < 16; ++it) {
    int b4 = it * 8 + (t >> 5);
    int n  = t & 31;
    unsigned long long v = *reinterpret_cast<const unsigned long long*>(
        lwb + b4 * 256 + ((n * 8) ^ ((b4 & 31) << 3)));
    *reinterpret_cast<unsigned long long*>(
        reinterpret_cast<char*>(qp) + (size_t)b4 * 32768 +
        (size_t)(n0 + n) * 8) = v;                  // 256B contiguous chunks
  }
}

// Fused dequant-GEMM (structure = round 5): 1024-thr block per 64x64 tile,
// 16 waves = 8 k-slices x 2 n-halves, barrier-free pipelined k-loop, LDS
// tree reduction, single coalesced store. All global accesses contiguous
// per wave (Xa fragment-linear, Qp packed) — no big-stride channel aliasing.
__global__ __launch_bounds__(1024, 4) void gemm_kernel(
    const unsigned short* __restrict__ xa, const unsigned short* __restrict__ qp,
    float* __restrict__ out) {
  __shared__ unsigned long long tbl[256];   // 2 KB, sign-folded bf16x4 codebook
  __shared__ float red[8][BM * RS];         // 8 x 9.2 KB partial half-tiles

  const int tid  = threadIdx.x;
  const int lane = tid & 63;
  const int wave = tid >> 6;                // 0..15
  const int wk   = wave >> 1;               // k-slice 0..7
  const int wn   = wave & 1;                // n-half 0..1
  const int l15  = lane & 15, l4 = lane >> 4;

  const int bid = blockIdx.x;               // 0..255
  const int nt  = (bid & 7) * 8 + ((bid >> 3) & 7);   // 0..63
  const int mt  = bid >> 6;                           // 0..3
  const int m0 = mt * BM, n0 = nt * BN;

  // ---- signed codebook table: tbl[i] = 4 packed bf16, tbl[i+128] = -tbl[i]
  if (tid < 256) {
    int r = tid & 127, sg = tid >> 7;
    unsigned long long v = 0;
#pragma unroll
    for (int j = 0; j < 4; ++j) {
      float f = (float)D4_I8[r * 4 + j] * 0.5f;
      unsigned int b = __float_as_uint(f) ^ (sg ? 0x80000000u : 0u);
      v |= (unsigned long long)(b >> 16) << (16 * j);
    }
    tbl[tid] = v;
  }
  __syncthreads();

  // ---- per-lane bases (contiguous wave access in both layouts)
  const unsigned short* aw =
      xa + ((size_t)(wk * 16) * 1024 + (m0 + l15) * 4 + l4) * 8;
  const unsigned short* qw =
      qp + (size_t)(wk * 16) * 16384 + (n0 + wn * 32 + l15) * 4 + l4;

  f32x4          acc[4][2] = {};
  unsigned short qbuf[3][2] = {};
  bf16x8         abuf[2][4];
  bf16x8         bbuf[2][2];

  auto qload = [&](int s, int t) {          // 2 x 128B-contiguous wave loads
    if (t < NH)
#pragma unroll
      for (int ni = 0; ni < 2; ++ni)
        qbuf[s][ni] = qw[(size_t)t * 16384 + ni * 64];
  };
  auto aload = [&](int s, int t) {          // 4 x 1KB-contiguous wave loads
    if (t < NH)
#pragma unroll
      for (int mi = 0; mi < 4; ++mi)
        abuf[s][mi] = *reinterpret_cast<const bf16x8*>(
            aw + (size_t)t * 8192 + mi * 512);
  };
  auto blook = [&](int s, int qs) {         // 4 ds_read_b64 table lookups
#pragma unroll
    for (int ni = 0; ni < 2; ++ni) {
      unsigned q = qbuf[qs][ni];
      union { unsigned long long u[2]; bf16x8 v; } c;
      c.u[0] = tbl[q & 255];
      c.u[1] = tbl[q >> 8];
      bbuf[s][ni] = c.v;
    }
  };

  // ---- prologue
  qload(0, 0);
  qload(1, 1);
  aload(0, 0);
  blook(0, 0);

  // ---- pipelined k-loop, fully unrolled (all buffer indices static)
#pragma unroll
  for (int t = 0; t < NH; ++t) {
    qload((t + 2) % 3, t + 2);          // indices, 2 ahead
    aload((t + 1) & 1, t + 1);          // A-fragments, 1 ahead
    blook((t + 1) & 1, (t + 1) % 3);    // lookups for t+1 before MFMAs of t
#pragma unroll
    for (int mi = 0; mi < 4; ++mi)
#pragma unroll
      for (int ni = 0; ni < 2; ++ni)
        acc[mi][ni] = __builtin_amdgcn_mfma_f32_16x16x32_bf16(
            abuf[t & 1][mi], bbuf[t & 1][ni], acc[mi][ni], 0, 0, 0);
  }

  // ---- 3-stage tree reduction over the 8 k-slices (per n-half)
  auto wtile = [&](int s) {
    float* rw = &red[s][0];
#pragma unroll
    for (int mi = 0; mi < 4; ++mi)
#pragma unroll
      for (int ni = 0; ni < 2; ++ni)
#pragma unroll
        for (int r = 0; r < 4; ++r)
          rw[(mi * 16 + l4 * 4 + r) * RS + ni * 16 + l15] = acc[mi][ni][r];
  };
  auto atile = [&](int s) {
    const float* rr = &red[s][0];
#pragma unroll
    for (int mi = 0; mi < 4; ++mi)
#pragma unroll
      for (int ni = 0; ni < 2; ++ni)
#pragma unroll
        for (int r = 0; r < 4; ++r)
          acc[mi][ni][r] += rr[(mi * 16 + l4 * 4 + r) * RS + ni * 16 + l15];
  };

  if (wk >= 4) wtile((wk - 4) * 2 + wn);
  __syncthreads();
  if (wk < 4) atile(wk * 2 + wn);
  __syncthreads();
  if (wk == 2 || wk == 3) wtile((wk - 2) * 2 + wn);
  __syncthreads();
  if (wk < 2) atile(wk * 2 + wn);
  __syncthreads();
  if (wk == 1) wtile(wn);
  __syncthreads();
  if (wk == 0) { atile(wn); wtile(wn); }   // final 64x32 tiles in slots 0,1
  __syncthreads();

  // ---- coalesced copy-out: 1024 threads x 1 float4 (16 KB tile)
  {
    const int row = tid >> 4;        // 0..63
    const int c4  = tid & 15;        // float4 column 0..15
    float4 v = *reinterpret_cast<const float4*>(
        &red[c4 >> 3][row * RS + (c4 & 7) * 4]);
    *reinterpret_cast<float4*>(
        &out[(size_t)(m0 + row) * MOUT + n0 + c4 * 4]) = v;
  }
}

extern "C" void kernel_launch(void* const* d_in, const int* in_sizes, int n_in,
                              void* d_out, int out_size, void* d_ws, size_t ws_size,
                              hipStream_t stream) {
  const float* inp = (const float*)d_in[0];
  const float* sw  = (const float*)d_in[1];
  const float* qs  = (const float*)d_in[2];
  const int*   qi  = (const int*)d_in[3];
  float* out = (float*)d_out;
  unsigned short* xa = (unsigned short*)d_ws;                  // 2 MB
  unsigned short* qp = (unsigned short*)((char*)d_ws + (4 << 20));  // 4 MB

  prep_kernel<<<512, 256, 0, stream>>>(inp, sw, qs, xa);
  repack_kernel<<<128, 256, 0, stream>>>(qi, qp);

  constexpr int GRID = (BATCH / BM) * (MOUT / BN);   // 4 * 64 = 256
  gemm_kernel<<<GRID, 1024, 0, stream>>>(xa, qp, out);
}